// Round 4
// baseline (1870.030 us; speedup 1.0000x reference)
//
#include <hip/hip_runtime.h>
#include <cstdint>

#define BATCH  4
#define LSEQ   2048
#define DMODEL 1024
#define NHEAD  16
#define HSIZE  64

typedef __attribute__((ext_vector_type(8))) short bf16x8;
typedef __attribute__((ext_vector_type(4))) float f32x4;

// ---------------------------------------------------------------------------
// XCD-aware bijective block swizzle (m157; valid when n % 8 == 0).
// ---------------------------------------------------------------------------
__device__ __forceinline__ int xcd_swz(int lin, int n) {
    return (lin & 7) * (n >> 3) + (lin >> 3);
}

// ---------------------------------------------------------------------------
// bf16 split helpers (round-to-nearest-even)
// ---------------------------------------------------------------------------
__device__ __forceinline__ unsigned short f2b(float f) {
    unsigned int u = __float_as_uint(f);
    return (unsigned short)((u + 0x7FFFu + ((u >> 16) & 1u)) >> 16);
}
__device__ __forceinline__ float b2f(unsigned short h) {
    return __uint_as_float(((unsigned int)h) << 16);
}
__device__ __forceinline__ void split2(float x, unsigned short& h, unsigned short& l) {
    h = f2b(x);
    l = f2b(x - b2f(h));
}

__device__ __forceinline__ void gld16(const void* g, void* l) {
    __builtin_amdgcn_global_load_lds(
        (const __attribute__((address_space(1))) unsigned int*)g,
        (__attribute__((address_space(3))) unsigned int*)l, 16, 0, 0);
}

// ---------------------------------------------------------------------------
// split fp32 -> bf16 hi/lo (grid-stride, float4)
// ---------------------------------------------------------------------------
__global__ void split_kernel(const float* __restrict__ in,
                             unsigned short* __restrict__ hi,
                             unsigned short* __restrict__ lo, int n4)
{
    for (int i = blockIdx.x * blockDim.x + threadIdx.x; i < n4;
         i += gridDim.x * blockDim.x) {
        const float4 v = ((const float4*)in)[i];
        ushort4 h, l;
        split2(v.x, h.x, l.x);
        split2(v.y, h.y, l.y);
        split2(v.z, h.z, l.z);
        split2(v.w, h.w, l.w);
        ((ushort4*)hi)[i] = h;
        ((ushort4*)lo)[i] = l;
    }
}

// ---------------------------------------------------------------------------
// transpose + split: in [K][N] fp32 -> hi/lo [N][K] bf16
// ---------------------------------------------------------------------------
__global__ __launch_bounds__(256)
void splitT_kernel(const float* __restrict__ in,
                   unsigned short* __restrict__ hi,
                   unsigned short* __restrict__ lo, int K, int N)
{
    __shared__ float t[32][33];
    const int k0 = blockIdx.y * 32, n0 = blockIdx.x * 32;
    const int tx = threadIdx.x & 7, ty = threadIdx.x >> 3;   // 8 x 32

    const float4 v = *(const float4*)(in + (size_t)(k0 + ty) * N + n0 + tx * 4);
    t[ty][tx * 4 + 0] = v.x;
    t[ty][tx * 4 + 1] = v.y;
    t[ty][tx * 4 + 2] = v.z;
    t[ty][tx * 4 + 3] = v.w;
    __syncthreads();

    const float x0 = t[tx * 4 + 0][ty], x1 = t[tx * 4 + 1][ty];
    const float x2 = t[tx * 4 + 2][ty], x3 = t[tx * 4 + 3][ty];
    ushort4 h, l;
    split2(x0, h.x, l.x);
    split2(x1, h.y, l.y);
    split2(x2, h.z, l.z);
    split2(x3, h.w, l.w);
    const size_t o = (size_t)(n0 + ty) * K + k0 + tx * 4;
    *(ushort4*)(hi + o) = h;
    *(ushort4*)(lo + o) = l;
}

// ---------------------------------------------------------------------------
// Split-bf16 MFMA GEMM: C = A@B + bias computed as Ah*Bh + Ah*Bl + Al*Bh
// (lo*lo dropped: ~2^-18 relative). A hi/lo [M][K] bf16, B hi/lo [N][K] bf16
// (pre-transposed). 128x128 tile, BK=32, 4 waves (2x2), each wave 64x64 =
// 4x4 frags of mfma_f32_16x16x32_bf16. m97 structure: linear LDS +
// global_load_lds width 16 (T2 swizzle deliberately omitted: NULL at 2-phase).
// MODE 0: scatter columns to q/k/v [B,NH,L,HS]; MODE 1: row-major C.
// ---------------------------------------------------------------------------
template<int MODE>
__global__ __launch_bounds__(256)
void mfma_gemm(const unsigned short* __restrict__ Ah, const unsigned short* __restrict__ Al,
               const unsigned short* __restrict__ Bh, const unsigned short* __restrict__ Bl,
               const float* __restrict__ bias,
               float* __restrict__ C0, float* __restrict__ C1, float* __restrict__ C2,
               int M, int N, int K)
{
    __shared__ __align__(16) unsigned short sAh[128 * 32];
    __shared__ __align__(16) unsigned short sAl[128 * 32];
    __shared__ __align__(16) unsigned short sBh[128 * 32];
    __shared__ __align__(16) unsigned short sBl[128 * 32];

    const int tid = threadIdx.x;
    const int lane = tid & 63, wave = tid >> 6;
    const int wm = wave >> 1, wn = wave & 1;

    // XCD swizzle over the whole 2D grid
    const int gx = gridDim.x;
    int lin = blockIdx.y * gx + blockIdx.x;
    lin = xcd_swz(lin, gx * gridDim.y);
    const int m0 = (lin / gx) * 128, n0 = (lin % gx) * 128;

    f32x4 acc[4][4];
#pragma unroll
    for (int mi = 0; mi < 4; ++mi)
#pragma unroll
        for (int ni = 0; ni < 4; ++ni) {
            acc[mi][ni][0] = 0.f; acc[mi][ni][1] = 0.f;
            acc[mi][ni][2] = 0.f; acc[mi][ni][3] = 0.f;
        }

    // staging: per wave, 32 rows of each array as 2 groups of 16 rows.
    // lane l covers row (l>>2), 16B chunk (l&3): LDS off = 8*l ushorts
    const int srow = lane >> 2;
    const int skc8 = (lane & 3) * 8;
    const int r0 = wave * 32;

    for (int kt = 0; kt < K; kt += 32) {
        __syncthreads();
#pragma unroll
        for (int g = 0; g < 2; ++g) {
            const int row = r0 + g * 16 + srow;
            const size_t ga = (size_t)(m0 + row) * K + kt + skc8;
            const size_t gb = (size_t)(n0 + row) * K + kt + skc8;
            unsigned short* la = sAh + (size_t)(r0 + g * 16) * 32;
            unsigned short* lb = sAl + (size_t)(r0 + g * 16) * 32;
            unsigned short* lc = sBh + (size_t)(r0 + g * 16) * 32;
            unsigned short* ld = sBl + (size_t)(r0 + g * 16) * 32;
            gld16(Ah + ga, la);
            gld16(Al + ga, lb);
            gld16(Bh + gb, lc);
            gld16(Bl + gb, ld);
        }
        __syncthreads();

        const int fr = lane & 15, fk8 = (lane >> 4) * 8;
        bf16x8 ah[4], al[4], bh[4], bl[4];
#pragma unroll
        for (int mi = 0; mi < 4; ++mi) {
            const int off = (wm * 64 + mi * 16 + fr) * 32 + fk8;
            ah[mi] = *(const bf16x8*)(sAh + off);
            al[mi] = *(const bf16x8*)(sAl + off);
        }
#pragma unroll
        for (int ni = 0; ni < 4; ++ni) {
            const int off = (wn * 64 + ni * 16 + fr) * 32 + fk8;
            bh[ni] = *(const bf16x8*)(sBh + off);
            bl[ni] = *(const bf16x8*)(sBl + off);
        }
#pragma unroll
        for (int mi = 0; mi < 4; ++mi)
#pragma unroll
            for (int ni = 0; ni < 4; ++ni) {
                acc[mi][ni] = __builtin_amdgcn_mfma_f32_16x16x32_bf16(ah[mi], bh[ni], acc[mi][ni], 0, 0, 0);
                acc[mi][ni] = __builtin_amdgcn_mfma_f32_16x16x32_bf16(ah[mi], bl[ni], acc[mi][ni], 0, 0, 0);
                acc[mi][ni] = __builtin_amdgcn_mfma_f32_16x16x32_bf16(al[mi], bh[ni], acc[mi][ni], 0, 0, 0);
            }
    }

    // epilogue: C/D frag layout col = lane&15, row = (lane>>4)*4 + r  [m89/m91]
    const int cn = lane & 15, cr = (lane >> 4) * 4;
#pragma unroll
    for (int ni = 0; ni < 4; ++ni) {
        const int col = n0 + wn * 64 + ni * 16 + cn;
        const float bv = bias[col];
        if (MODE == 1) {
#pragma unroll
            for (int mi = 0; mi < 4; ++mi) {
                const int rowb = m0 + wm * 64 + mi * 16 + cr;
#pragma unroll
                for (int r = 0; r < 4; ++r)
                    C0[(size_t)(rowb + r) * N + col] = acc[mi][ni][r] + bv;
            }
        } else {
            const int sel = col >> 10, d = col & 1023;
            const int head = d >> 6, hs = d & 63;
            float* dst = (sel == 0) ? C0 : (sel == 1) ? C1 : C2;
#pragma unroll
            for (int mi = 0; mi < 4; ++mi) {
                const int rowb = m0 + wm * 64 + mi * 16 + cr;
#pragma unroll
                for (int r = 0; r < 4; ++r) {
                    const int m = rowb + r;
                    const int bb = m >> 11, l = m & (LSEQ - 1);
                    dst[(((size_t)bb * NHEAD + head) * LSEQ + l) * HSIZE + hs] =
                        acc[mi][ni][r] + bv;
                }
            }
        }
    }
}

// ---------------------------------------------------------------------------
// Flash-style causal attention with relative positions (fp32 VALU).
// Srel[i,j] = q_i . Er[L-1 + j - i]  (skew() reduced algebraically).
// Er LDS chunks XOR-swizzled by ((row>>1)&3); ev loads shared across equal
// cc-rr diffs (5 loads / d0-step). T14 async-stage: global loads for tile
// jt+1 are ISSUED before this tile's S-loop (registers only, no LDS touch —
// pure code motion, barrier structure identical); the compiler's vmcnt drain
// at the next barrier completes them after ~2100cy of S compute.
// Output written as bf16 hi/lo, feeding the split-bf16 proj GEMM.
// ---------------------------------------------------------------------------
__global__ __launch_bounds__(256)
void attn_kernel(const float* __restrict__ Q, const float* __restrict__ K,
                 const float* __restrict__ V, const float* __restrict__ Er,
                 unsigned short* __restrict__ Yh, unsigned short* __restrict__ Yl)
{
    const int nqt = LSEQ / 64;            // 32
    const int lin = xcd_swz(blockIdx.x, BATCH * NHEAD * nqt);
    const int bh = lin / nqt;
    const int qt = lin % nqt;
    const int i0 = qt * 64;
    const int bidx = bh >> 4, hidx = bh & 15;

    const float* Qp = Q + (size_t)bh * LSEQ * HSIZE;
    const float* Kp = K + (size_t)bh * LSEQ * HSIZE;
    const float* Vp = V + (size_t)bh * LSEQ * HSIZE;

    // 224 rows x 68 floats = 59.5 KB
    __shared__ float smem[224 * 68];
    float (*q_s)[68]  = (float(*)[68])(smem);             // 64 rows [i][d]
    float (*k_s)[68]  = (float(*)[68])(smem + 64 * 68);   // 32 rows [j][d]
    float (*v_s)[68]  = (float(*)[68])(smem + 96 * 68);   // 32 rows [j][d]
    float (*er_s)[68] = (float(*)[68])(smem + 128 * 68);  // 96 rows [t][swizzled d]
    float (*p_s)[36]  = (float(*)[36])(smem + 128 * 68);  // 64x36, aliases er region

    const int tid = threadIdx.x;
    const int tx = tid & 15, ty = tid >> 4;

#pragma unroll
    for (int rr = 0; rr < 4; ++rr) {
        const int r = ty * 4 + rr;
        *(float4*)&q_s[r][tx * 4] =
            *(const float4*)(Qp + (size_t)(i0 + r) * HSIZE + tx * 4);
    }

    float acc_o[4][4];
    float m_run[4], l_run[4];
#pragma unroll
    for (int rr = 0; rr < 4; ++rr) {
        m_run[rr] = -3.0e38f; l_run[rr] = 0.f;
#pragma unroll
        for (int cc = 0; cc < 4; ++cc) acc_o[rr][cc] = 0.f;
    }

    const float cexp = 0.18033688011112042f;  // (1/sqrt(64)) * log2(e)

    const int jr = tid >> 4;            // staging row 0..15
    const int d4 = (tid & 15) * 4;      // staging col (global, unswizzled)
    const int sc = tid & 15;            // staging chunk index 0..15
    const int ntiles = 2 * qt + 2;

    // er rows by diagonal diff dd = (cc - rr) + 3 in [0,5); jt-invariant
    const int tb = 63 + tx * 2 - ty * 4;
    int trowD[5], tswD[5];
#pragma unroll
    for (int dd = 0; dd < 5; ++dd) {
        trowD[dd] = tb + dd - 3;                // in [0,94]
        tswD[dd]  = (trowD[dd] >> 1) & 3;
    }

    // ---- T14 prefetch registers: K/V (2+2 float4) + Er (6 float4) ----
    float4 kreg[2], vreg[2], ereg[6];
    {   // issue loads for tile 0
        const int j0 = 0;
        const int e0 = (LSEQ - 64) + j0 - i0;
        kreg[0] = *(const float4*)(Kp + (size_t)(j0 + jr) * HSIZE + d4);
        kreg[1] = *(const float4*)(Kp + (size_t)(j0 + jr + 16) * HSIZE + d4);
        vreg[0] = *(const float4*)(Vp + (size_t)(j0 + jr) * HSIZE + d4);
        vreg[1] = *(const float4*)(Vp + (size_t)(j0 + jr + 16) * HSIZE + d4);
#pragma unroll
        for (int it = 0; it < 6; ++it) {
            const int erow = e0 + it * 16 + jr;
            ereg[it] = (erow < LSEQ)
                ? *(const float4*)(Er + (size_t)erow * HSIZE + d4)
                : make_float4(0.f, 0.f, 0.f, 0.f);
        }
    }

    for (int jt = 0; jt < ntiles; ++jt) {
        const int j0 = jt * 32;

        __syncthreads();   // prev-tile PV/er reads done; drains prefetch vmcnt
        // ---- LDS staging from prefetch registers ----
        *(float4*)&k_s[jr][d4]      = kreg[0];
        *(float4*)&k_s[jr + 16][d4] = kreg[1];
        *(float4*)&v_s[jr][d4]      = vreg[0];
        *(float4*)&v_s[jr + 16][d4] = vreg[1];
#pragma unroll
        for (int it = 0; it < 6; ++it) {
            const int trow = it * 16 + jr;
            const int csw = (sc & 12) | ((sc & 3) ^ ((trow >> 1) & 3));
            *(float4*)&er_s[trow][csw * 4] = ereg[it];
        }
        __syncthreads();

        // ---- issue next tile's global loads (in flight across S compute) ----
        if (jt + 1 < ntiles) {
            const int j1 = j0 + 32;
            const int e1 = (LSEQ - 64) + j1 - i0;
            kreg[0] = *(const float4*)(Kp + (size_t)(j1 + jr) * HSIZE + d4);
            kreg[1] = *(const float4*)(Kp + (size_t)(j1 + jr + 16) * HSIZE + d4);
            vreg[0] = *(const float4*)(Vp + (size_t)(j1 + jr) * HSIZE + d4);
            vreg[1] = *(const float4*)(Vp + (size_t)(j1 + jr + 16) * HSIZE + d4);
#pragma unroll
            for (int it = 0; it < 6; ++it) {
                const int erow = e1 + it * 16 + jr;
                ereg[it] = (erow < LSEQ)
                    ? *(const float4*)(Er + (size_t)erow * HSIZE + d4)
                    : make_float4(0.f, 0.f, 0.f, 0.f);
            }
        }

        // ---- S = q.k + q.Er[shift]  (64x32 tile) ----
        float acc_s[4][2];
#pragma unroll
        for (int rr = 0; rr < 4; ++rr) { acc_s[rr][0] = 0.f; acc_s[rr][1] = 0.f; }

#pragma unroll 4
        for (int d0 = 0; d0 < 64; d0 += 4) {
            const int c = d0 >> 2;
            float4 qv[4];
#pragma unroll
            for (int rr = 0; rr < 4; ++rr)
                qv[rr] = *(const float4*)&q_s[ty * 4 + rr][d0];
            float4 kv[2];
            kv[0] = *(const float4*)&k_s[tx * 2][d0];
            kv[1] = *(const float4*)&k_s[tx * 2 + 1][d0];
            float4 evd[5];
#pragma unroll
            for (int dd = 0; dd < 5; ++dd) {
                const int csw = (c & 12) | ((c & 3) ^ tswD[dd]);
                evd[dd] = *(const float4*)&er_s[trowD[dd]][csw * 4];
            }
#pragma unroll
            for (int rr = 0; rr < 4; ++rr)
#pragma unroll
                for (int cc = 0; cc < 2; ++cc) {
                    const float4 ev = evd[cc - rr + 3];
                    float s = acc_s[rr][cc];
                    s = fmaf(qv[rr].x, kv[cc].x + ev.x, s);
                    s = fmaf(qv[rr].y, kv[cc].y + ev.y, s);
                    s = fmaf(qv[rr].z, kv[cc].z + ev.z, s);
                    s = fmaf(qv[rr].w, kv[cc].w + ev.w, s);
                    acc_s[rr][cc] = s;
                }
        }

        if (jt >= 2 * qt) {
#pragma unroll
            for (int rr = 0; rr < 4; ++rr)
#pragma unroll
                for (int cc = 0; cc < 2; ++cc)
                    if (j0 + tx * 2 + cc > i0 + ty * 4 + rr)
                        acc_s[rr][cc] = -3.0e38f;
        }

        // ---- online softmax (rows shared by the 16 tx lanes) ----
        float pv[4][2];
#pragma unroll
        for (int rr = 0; rr < 4; ++rr) {
            float mt = fmaxf(acc_s[rr][0], acc_s[rr][1]);
            mt = fmaxf(mt, __shfl_xor(mt, 1, 16));
            mt = fmaxf(mt, __shfl_xor(mt, 2, 16));
            mt = fmaxf(mt, __shfl_xor(mt, 4, 16));
            mt = fmaxf(mt, __shfl_xor(mt, 8, 16));
            const float mnew  = fmaxf(m_run[rr], mt);
            const float alpha = __builtin_amdgcn_exp2f((m_run[rr] - mnew) * cexp);
            m_run[rr] = mnew;
            const float p0 = __builtin_amdgcn_exp2f((acc_s[rr][0] - mnew) * cexp);
            const float p1 = __builtin_amdgcn_exp2f((acc_s[rr][1] - mnew) * cexp);
            pv[rr][0] = p0; pv[rr][1] = p1;
            float rs = p0 + p1;
            rs += __shfl_xor(rs, 1, 16);
            rs += __shfl_xor(rs, 2, 16);
            rs += __shfl_xor(rs, 4, 16);
            rs += __shfl_xor(rs, 8, 16);
            l_run[rr] = l_run[rr] * alpha + rs;
#pragma unroll
            for (int cc = 0; cc < 4; ++cc) acc_o[rr][cc] *= alpha;
        }

        __syncthreads();   // er reads done before P overwrites its region
#pragma unroll
        for (int rr = 0; rr < 4; ++rr) {
            p_s[ty * 4 + rr][tx * 2]     = pv[rr][0];
            p_s[ty * 4 + rr][tx * 2 + 1] = pv[rr][1];
        }
        __syncthreads();

        // ---- O += P @ V ----
#pragma unroll 2
        for (int js = 0; js < 32; js += 4) {
            float4 pb[4];
#pragma unroll
            for (int rr = 0; rr < 4; ++rr)
                pb[rr] = *(const float4*)&p_s[ty * 4 + rr][js];
            float4 vv[4];
#pragma unroll
            for (int jj = 0; jj < 4; ++jj)
                vv[jj] = *(const float4*)&v_s[js + jj][tx * 4];
#pragma unroll
            for (int rr = 0; rr < 4; ++rr) {
                const float p0 = pb[rr].x, p1 = pb[rr].y, p2 = pb[rr].z, p3 = pb[rr].w;
                acc_o[rr][0] = fmaf(p3, vv[3].x, fmaf(p2, vv[2].x, fmaf(p1, vv[1].x, fmaf(p0, vv[0].x, acc_o[rr][0]))));
                acc_o[rr][1] = fmaf(p3, vv[3].y, fmaf(p2, vv[2].y, fmaf(p1, vv[1].y, fmaf(p0, vv[0].y, acc_o[rr][1]))));
                acc_o[rr][2] = fmaf(p3, vv[3].z, fmaf(p2, vv[2].z, fmaf(p1, vv[1].z, fmaf(p0, vv[0].z, acc_o[rr][2]))));
                acc_o[rr][3] = fmaf(p3, vv[3].w, fmaf(p2, vv[2].w, fmaf(p1, vv[1].w, fmaf(p0, vv[0].w, acc_o[rr][3]))));
            }
        }
    }

    // normalize, split to bf16 hi/lo, write y as [B, L, D]
#pragma unroll
    for (int rr = 0; rr < 4; ++rr) {
        const float inv = 1.0f / l_run[rr];
        const int r = ty * 4 + rr;
        ushort4 hv, lv;
        split2(acc_o[rr][0] * inv, hv.x, lv.x);
        split2(acc_o[rr][1] * inv, hv.y, lv.y);
        split2(acc_o[rr][2] * inv, hv.z, lv.z);
        split2(acc_o[rr][3] * inv, hv.w, lv.w);
        const size_t o = (size_t)(bidx * LSEQ + i0 + r) * DMODEL + hidx * HSIZE + tx * 4;
        *(ushort4*)(Yh + o) = hv;
        *(ushort4*)(Yl + o) = lv;
    }
}

// ---------------------------------------------------------------------------
extern "C" void kernel_launch(void* const* d_in, const int* in_sizes, int n_in,
                              void* d_out, int out_size, void* d_ws, size_t ws_size,
                              hipStream_t stream)
{
    (void)in_sizes; (void)n_in; (void)out_size; (void)ws_size;
    const float* x      = (const float*)d_in[0];
    const float* W_attn = (const float*)d_in[1];
    const float* b_attn = (const float*)d_in[2];
    const float* Er     = (const float*)d_in[3];
    const float* W_proj = (const float*)d_in[4];
    const float* b_proj = (const float*)d_in[5];
    float* out = (float*)d_out;

    // workspace layout (~151 MB): yh/yl alias xh/xl (x fully consumed by
    // GEMM1 before attn writes y; same-stream serialization guarantees order)
    char* ws = (char*)d_ws;
    size_t off = 0;
    float* qb = (float*)(ws + off); off += (size_t)BATCH * NHEAD * LSEQ * HSIZE * 4;
    float* kb = (float*)(ws + off); off += (size_t)BATCH * NHEAD * LSEQ * HSIZE * 4;
    float* vb = (float*)(ws + off); off += (size_t)BATCH * NHEAD * LSEQ * HSIZE * 4;
    unsigned short* xh = (unsigned short*)(ws + off); off += (size_t)BATCH * LSEQ * DMODEL * 2;
    unsigned short* xl = (unsigned short*)(ws + off); off += (size_t)BATCH * LSEQ * DMODEL * 2;
    unsigned short* wah = (unsigned short*)(ws + off); off += (size_t)3 * DMODEL * DMODEL * 2;
    unsigned short* wal = (unsigned short*)(ws + off); off += (size_t)3 * DMODEL * DMODEL * 2;
    unsigned short* wph = (unsigned short*)(ws + off); off += (size_t)DMODEL * DMODEL * 2;
    unsigned short* wpl = (unsigned short*)(ws + off); off += (size_t)DMODEL * DMODEL * 2;
    unsigned short* yh = xh;
    unsigned short* yl = xl;

    const int M = BATCH * LSEQ;  // 8192

    // 0) split inputs to bf16 hi/lo (weights transposed to [N][K])
    split_kernel<<<2048, 256, 0, stream>>>(x, xh, xl, (BATCH * LSEQ * DMODEL) / 4);
    splitT_kernel<<<dim3(3 * DMODEL / 32, DMODEL / 32), 256, 0, stream>>>(
        W_attn, wah, wal, DMODEL, 3 * DMODEL);
    splitT_kernel<<<dim3(DMODEL / 32, DMODEL / 32), 256, 0, stream>>>(
        W_proj, wph, wpl, DMODEL, DMODEL);

    // 1) qkv = x @ W_attn + b_attn  (MFMA split-bf16), scattered to q/k/v
    mfma_gemm<0><<<dim3(3 * DMODEL / 128, M / 128), 256, 0, stream>>>(
        xh, xl, wah, wal, b_attn, qb, kb, vb, M, 3 * DMODEL, DMODEL);

    // 2) fused causal attention with relative positions -> y (bf16 hi/lo)
    attn_kernel<<<BATCH * NHEAD * (LSEQ / 64), 256, 0, stream>>>(qb, kb, vb, Er, yh, yl);

    // 3) out = y @ W_proj + b_proj  (MFMA split-bf16)
    mfma_gemm<1><<<dim3(DMODEL / 128, M / 128), 256, 0, stream>>>(
        yh, yl, wph, wpl, b_proj, out, nullptr, nullptr, M, DMODEL, DMODEL);
}

// Round 7
// 752.821 us; speedup vs baseline: 2.4840x; 2.4840x over previous
//
#include <hip/hip_runtime.h>
#include <cstdint>

#define BATCH  4
#define LSEQ   2048
#define DMODEL 1024
#define NHEAD  16
#define HSIZE  64

typedef __attribute__((ext_vector_type(8))) short bf16x8;
typedef __attribute__((ext_vector_type(4))) float f32x4;
typedef unsigned short u16;
typedef unsigned int u32;

// ---------------------------------------------------------------------------
// XCD-aware bijective block swizzle (m157; valid when n % 8 == 0).
// ---------------------------------------------------------------------------
__device__ __forceinline__ int xcd_swz(int lin, int n) {
    return (lin & 7) * (n >> 3) + (lin >> 3);
}

// ---------------------------------------------------------------------------
// bf16 split helpers (round-to-nearest-even)
// ---------------------------------------------------------------------------
__device__ __forceinline__ u16 f2b(float f) {
    unsigned int u = __float_as_uint(f);
    return (u16)((u + 0x7FFFu + ((u >> 16) & 1u)) >> 16);
}
__device__ __forceinline__ float b2f(u16 h) {
    return __uint_as_float(((unsigned int)h) << 16);
}
__device__ __forceinline__ void split2(float x, u16& h, u16& l) {
    h = f2b(x);
    l = f2b(x - b2f(h));
}

__device__ __forceinline__ void gld16(const void* g, void* l) {
    __builtin_amdgcn_global_load_lds(
        (const __attribute__((address_space(1))) unsigned int*)g,
        (__attribute__((address_space(3))) unsigned int*)l, 16, 0, 0);
}

// ---------------------------------------------------------------------------
// split fp32 -> bf16 hi/lo (grid-stride, float4)
// ---------------------------------------------------------------------------
__global__ void split_kernel(const float* __restrict__ in,
                             u16* __restrict__ hi, u16* __restrict__ lo, int n4)
{
    for (int i = blockIdx.x * blockDim.x + threadIdx.x; i < n4;
         i += gridDim.x * blockDim.x) {
        const float4 v = ((const float4*)in)[i];
        ushort4 h, l;
        split2(v.x, h.x, l.x);
        split2(v.y, h.y, l.y);
        split2(v.z, h.z, l.z);
        split2(v.w, h.w, l.w);
        ((ushort4*)hi)[i] = h;
        ((ushort4*)lo)[i] = l;
    }
}

// ---------------------------------------------------------------------------
// transpose + split: in [K][N] fp32 -> hi/lo [N][K] bf16
// ---------------------------------------------------------------------------
__global__ __launch_bounds__(256)
void splitT_kernel(const float* __restrict__ in,
                   u16* __restrict__ hi, u16* __restrict__ lo, int K, int N)
{
    __shared__ float t[32][33];
    const int k0 = blockIdx.y * 32, n0 = blockIdx.x * 32;
    const int tx = threadIdx.x & 7, ty = threadIdx.x >> 3;   // 8 x 32

    const float4 v = *(const float4*)(in + (size_t)(k0 + ty) * N + n0 + tx * 4);
    t[ty][tx * 4 + 0] = v.x;
    t[ty][tx * 4 + 1] = v.y;
    t[ty][tx * 4 + 2] = v.z;
    t[ty][tx * 4 + 3] = v.w;
    __syncthreads();

    const float x0 = t[tx * 4 + 0][ty], x1 = t[tx * 4 + 1][ty];
    const float x2 = t[tx * 4 + 2][ty], x3 = t[tx * 4 + 3][ty];
    ushort4 h, l;
    split2(x0, h.x, l.x);
    split2(x1, h.y, l.y);
    split2(x2, h.z, l.z);
    split2(x3, h.w, l.w);
    const size_t o = (size_t)(n0 + ty) * K + k0 + tx * 4;
    *(ushort4*)(hi + o) = h;
    *(ushort4*)(lo + o) = l;
}

// ---------------------------------------------------------------------------
// Split-bf16 MFMA GEMM (m97 structure, HW-validated round 4).
// MODE 0: epilogue splits to bf16 hi/lo and scatters to q/k/v [B,NH,L,HS].
// MODE 1: row-major fp32 C.
// ---------------------------------------------------------------------------
template<int MODE>
__global__ __launch_bounds__(256)
void mfma_gemm(const u16* __restrict__ Ah, const u16* __restrict__ Al,
               const u16* __restrict__ Bh, const u16* __restrict__ Bl,
               const float* __restrict__ bias, float* __restrict__ C0,
               u16* __restrict__ Qh, u16* __restrict__ Ql,
               u16* __restrict__ Kh, u16* __restrict__ Kl,
               u16* __restrict__ Vh, u16* __restrict__ Vl,
               int M, int N, int K)
{
    __shared__ __align__(16) u16 sAh[128 * 32];
    __shared__ __align__(16) u16 sAl[128 * 32];
    __shared__ __align__(16) u16 sBh[128 * 32];
    __shared__ __align__(16) u16 sBl[128 * 32];

    const int tid = threadIdx.x;
    const int lane = tid & 63, wave = tid >> 6;
    const int wm = wave >> 1, wn = wave & 1;

    const int gx = gridDim.x;
    int lin = blockIdx.y * gx + blockIdx.x;
    lin = xcd_swz(lin, gx * gridDim.y);
    const int m0 = (lin / gx) * 128, n0 = (lin % gx) * 128;

    f32x4 acc[4][4];
#pragma unroll
    for (int mi = 0; mi < 4; ++mi)
#pragma unroll
        for (int ni = 0; ni < 4; ++ni) {
            acc[mi][ni][0] = 0.f; acc[mi][ni][1] = 0.f;
            acc[mi][ni][2] = 0.f; acc[mi][ni][3] = 0.f;
        }

    const int srow = lane >> 2;
    const int skc8 = (lane & 3) * 8;
    const int r0 = wave * 32;

    for (int kt = 0; kt < K; kt += 32) {
        __syncthreads();
#pragma unroll
        for (int g = 0; g < 2; ++g) {
            const int row = r0 + g * 16 + srow;
            const size_t ga = (size_t)(m0 + row) * K + kt + skc8;
            const size_t gb = (size_t)(n0 + row) * K + kt + skc8;
            u16* la = sAh + (size_t)(r0 + g * 16) * 32;
            u16* lb = sAl + (size_t)(r0 + g * 16) * 32;
            u16* lc = sBh + (size_t)(r0 + g * 16) * 32;
            u16* ld = sBl + (size_t)(r0 + g * 16) * 32;
            gld16(Ah + ga, la);
            gld16(Al + ga, lb);
            gld16(Bh + gb, lc);
            gld16(Bl + gb, ld);
        }
        __syncthreads();

        const int fr = lane & 15, fk8 = (lane >> 4) * 8;
        bf16x8 ah[4], al[4], bh[4], bl[4];
#pragma unroll
        for (int mi = 0; mi < 4; ++mi) {
            const int off = (wm * 64 + mi * 16 + fr) * 32 + fk8;
            ah[mi] = *(const bf16x8*)(sAh + off);
            al[mi] = *(const bf16x8*)(sAl + off);
        }
#pragma unroll
        for (int ni = 0; ni < 4; ++ni) {
            const int off = (wn * 64 + ni * 16 + fr) * 32 + fk8;
            bh[ni] = *(const bf16x8*)(sBh + off);
            bl[ni] = *(const bf16x8*)(sBl + off);
        }
#pragma unroll
        for (int mi = 0; mi < 4; ++mi)
#pragma unroll
            for (int ni = 0; ni < 4; ++ni) {
                acc[mi][ni] = __builtin_amdgcn_mfma_f32_16x16x32_bf16(ah[mi], bh[ni], acc[mi][ni], 0, 0, 0);
                acc[mi][ni] = __builtin_amdgcn_mfma_f32_16x16x32_bf16(ah[mi], bl[ni], acc[mi][ni], 0, 0, 0);
                acc[mi][ni] = __builtin_amdgcn_mfma_f32_16x16x32_bf16(al[mi], bh[ni], acc[mi][ni], 0, 0, 0);
            }
    }

    // C/D frag layout: col = lane&15, row = (lane>>4)*4 + r  [m89/m91, HW-validated]
    const int cn = lane & 15, cr = (lane >> 4) * 4;
#pragma unroll
    for (int ni = 0; ni < 4; ++ni) {
        const int col = n0 + wn * 64 + ni * 16 + cn;
        const float bv = bias[col];
        if (MODE == 1) {
#pragma unroll
            for (int mi = 0; mi < 4; ++mi) {
                const int rowb = m0 + wm * 64 + mi * 16 + cr;
#pragma unroll
                for (int r = 0; r < 4; ++r)
                    C0[(size_t)(rowb + r) * N + col] = acc[mi][ni][r] + bv;
            }
        } else {
            const int sel = col >> 10, d = col & 1023;
            const int head = d >> 6, hs = d & 63;
            u16* dh = (sel == 0) ? Qh : (sel == 1) ? Kh : Vh;
            u16* dl = (sel == 0) ? Ql : (sel == 1) ? Kl : Vl;
#pragma unroll
            for (int mi = 0; mi < 4; ++mi) {
                const int rowb = m0 + wm * 64 + mi * 16 + cr;
#pragma unroll
                for (int r = 0; r < 4; ++r) {
                    const int m = rowb + r;
                    const int bb = m >> 11, l = m & (LSEQ - 1);
                    const size_t idx = (((size_t)bb * NHEAD + head) * LSEQ + l) * HSIZE + hs;
                    u16 h, lo;
                    split2(acc[mi][ni][r] + bv, h, lo);
                    dh[idx] = h;
                    dl[idx] = lo;
                }
            }
        }
    }
}

// ---------------------------------------------------------------------------
// MFMA flash attention with relative positions (split-bf16, 3-term).
// Block = (b,h,qtile of 64 rows); 4 waves, wave w owns q rows [16w,16w+16).
// KV tile 32.  Rolling-R: Srel[i,j] = q_i . Er[L-1+j-i]; per q-tile, tile jt
// needs Er-window [e0(jt), e0(jt)+96) which shifts by 32/tile -> persistent
// fp32 ring[64][101] (wave-private rows), compute only the 32 NEW rows/tile
// (12 MFMAs); 2-round prologue fills slots [0,64).
//   write slot = 32*((jt+2)%3) + t_new;  read slot = (32*(jt%3)+t_local)%96,
//   t_local = 63 + jc - sr.
// Q held in registers as A-fragments (no LDS).  K/Er staged [32][64] swizzled
// c^(row&7); V^T staged as packed-u32 [64][16] and P [64][32], both swizzled
// chunk ^ ((row+(row>>2))&3).  2 barriers per tile (ring/P rows wave-private).
// T5: s_setprio(1) around MFMA clusters (inter-block phase diversity at
// 2 blocks/CU; m191 attn +4-7%).
// ---------------------------------------------------------------------------
__global__ __launch_bounds__(256)
void attn_kernel(const u16* __restrict__ Qh, const u16* __restrict__ Ql,
                 const u16* __restrict__ Kh, const u16* __restrict__ Kl,
                 const u16* __restrict__ Vh, const u16* __restrict__ Vl,
                 const u16* __restrict__ Eh, const u16* __restrict__ El,
                 u16* __restrict__ Yh, u16* __restrict__ Yl)
{
    const int nqt = LSEQ / 64;            // 32
    const int lin = xcd_swz(blockIdx.x, BATCH * NHEAD * nqt);
    const int bh = lin / nqt;
    const int qt = (nqt - 1) - (lin % nqt);   // longest blocks first
    const int i0 = qt * 64;
    const int bidx = bh >> 4, hidx = bh & 15;

    const size_t bho = (size_t)bh * LSEQ * HSIZE;
    const u16* Qph = Qh + bho; const u16* Qpl = Ql + bho;
    const u16* Kph = Kh + bho; const u16* Kpl = Kl + bho;
    const u16* Vph = Vh + bho; const u16* Vpl = Vl + bho;

    __shared__ __align__(16) unsigned char smem[58624];
    u16* k_h  = (u16*)(smem);              // [32][64] 4096B
    u16* k_l  = (u16*)(smem + 4096);
    u16* vt_h = (u16*)(smem + 8192);       // [64][16] u32-packed (V^T) 4096B
    u16* vt_l = (u16*)(smem + 12288);
    u16* e_h  = (u16*)(smem + 16384);      // [32][64] 4096B (new window rows)
    u16* e_l  = (u16*)(smem + 20480);
    u16* p_h  = (u16*)(smem + 24576);      // [64][32] 4096B
    u16* p_l  = (u16*)(smem + 28672);
    float* ring = (float*)(smem + 32768);  // [64][101] fp32, 25856B

    const int tid = threadIdx.x;
    const int lane = tid & 63, w = tid >> 6;
    const int l4 = lane & 15, lh = lane >> 4;

    // ---- Q A-fragments in registers (rows 16w+l4, chunk ks*4+lh) ----
    bf16x8 aqh[2], aql[2];
#pragma unroll
    for (int ks = 0; ks < 2; ++ks) {
        const size_t qoff = (size_t)(i0 + 16 * w + l4) * 64 + ks * 32 + lh * 8;
        aqh[ks] = *(const bf16x8*)(Qph + qoff);
        aql[ks] = *(const bf16x8*)(Qpl + qoff);
    }

    f32x4 acc_o[4];
#pragma unroll
    for (int i = 0; i < 4; ++i) {
        acc_o[i][0] = 0.f; acc_o[i][1] = 0.f; acc_o[i][2] = 0.f; acc_o[i][3] = 0.f;
    }
    float m_run[4], l_run[4];
#pragma unroll
    for (int i = 0; i < 4; ++i) { m_run[i] = -3.0e38f; l_run[i] = 0.f; }

    const float cexp = 0.18033688011112042f;  // (1/sqrt(64)) * log2(e)
    const int e0base = LSEQ - 64 - i0;        // e0(jt=0) >= 0
    const int ntiles = 2 * qt + 2;

    // stage 32 Er rows [g0, g0+32) into e_h/e_l (zero past L)
    const int ser = tid >> 3, sec = tid & 7;          // row 0..31, chunk 0..7
    auto stage_er = [&](int g0) {
        const int g = g0 + ser;
        bf16x8 zh = {0, 0, 0, 0, 0, 0, 0, 0}, zl = {0, 0, 0, 0, 0, 0, 0, 0};
        if (g < LSEQ) {
            zh = *(const bf16x8*)(Eh + (size_t)g * 64 + sec * 8);
            zl = *(const bf16x8*)(El + (size_t)g * 64 + sec * 8);
        }
        const int cs = sec ^ (ser & 7);
        *(bf16x8*)(e_h + ser * 64 + cs * 8) = zh;
        *(bf16x8*)(e_l + ser * 64 + cs * 8) = zl;
    };

    // 12 MFMAs over the staged 32 rows -> ring slots [slotbase, slotbase+32)
    auto compute_R = [&](int slotbase) {
        f32x4 racc[2];
#pragma unroll
        for (int i = 0; i < 2; ++i) { racc[i][0]=0.f; racc[i][1]=0.f; racc[i][2]=0.f; racc[i][3]=0.f; }
        __builtin_amdgcn_s_setprio(1);
#pragma unroll
        for (int ks = 0; ks < 2; ++ks)
#pragma unroll
            for (int nf = 0; nf < 2; ++nf) {
                const int re = nf * 16 + l4;
                const int cb = (ks * 4 + lh) ^ (re & 7);
                const bf16x8 beh = *(const bf16x8*)(e_h + re * 64 + cb * 8);
                const bf16x8 bel = *(const bf16x8*)(e_l + re * 64 + cb * 8);
                racc[nf] = __builtin_amdgcn_mfma_f32_16x16x32_bf16(aqh[ks], beh, racc[nf], 0, 0, 0);
                racc[nf] = __builtin_amdgcn_mfma_f32_16x16x32_bf16(aqh[ks], bel, racc[nf], 0, 0, 0);
                racc[nf] = __builtin_amdgcn_mfma_f32_16x16x32_bf16(aql[ks], beh, racc[nf], 0, 0, 0);
            }
        __builtin_amdgcn_s_setprio(0);
#pragma unroll
        for (int nf = 0; nf < 2; ++nf)
#pragma unroll
            for (int r = 0; r < 4; ++r)
                ring[(16 * w + lh * 4 + r) * 101 + slotbase + nf * 16 + l4] = racc[nf][r];
    };

    // ---- prologue: fill ring slots [0,64) = window-0 t_local [0,64) ----
#pragma unroll
    for (int p = 0; p < 2; ++p) {
        __syncthreads();
        stage_er(e0base + 32 * p);
        __syncthreads();
        compute_R(32 * p);
    }

    for (int jt = 0; jt < ntiles; ++jt) {
        const int j0 = jt * 32;
        const int phR = jt % 3;               // read phase
        const int phW = (jt + 2) % 3;         // write phase (t_local 64..95)

        __syncthreads();  // B1: prev-tile PV reads + prev R-MFMA e-reads done
        {
            // K [32][64] swizzled
            const int cs = sec ^ (ser & 7);
            *(bf16x8*)(k_h + ser * 64 + cs * 8) =
                *(const bf16x8*)(Kph + (size_t)(j0 + ser) * 64 + sec * 8);
            *(bf16x8*)(k_l + ser * 64 + cs * 8) =
                *(const bf16x8*)(Kpl + (size_t)(j0 + ser) * 64 + sec * 8);
            // V^T packed u32 [64][16]: u32 jp packs (j=2jp, 2jp+1) at dim d
            const int jp = tid >> 4, d4 = (tid & 15) * 4;
            const ushort4 hA = *(const ushort4*)(Vph + (size_t)(j0 + 2 * jp) * 64 + d4);
            const ushort4 hB = *(const ushort4*)(Vph + (size_t)(j0 + 2 * jp + 1) * 64 + d4);
            const ushort4 lA = *(const ushort4*)(Vpl + (size_t)(j0 + 2 * jp) * 64 + d4);
            const ushort4 lB = *(const ushort4*)(Vpl + (size_t)(j0 + 2 * jp + 1) * 64 + d4);
            const u16 ha[4] = {hA.x, hA.y, hA.z, hA.w}, hb[4] = {hB.x, hB.y, hB.z, hB.w};
            const u16 la[4] = {lA.x, lA.y, lA.z, lA.w}, lb[4] = {lB.x, lB.y, lB.z, lB.w};
            const int cq = jp >> 2, co = jp & 3;
#pragma unroll
            for (int i = 0; i < 4; ++i) {
                const int d = d4 + i;
                const int fd = (d + (d >> 2)) & 3;
                const int cs2 = cq ^ fd;
                *(u32*)(vt_h + d * 32 + cs2 * 8 + co * 2) = (u32)ha[i] | ((u32)hb[i] << 16);
                *(u32*)(vt_l + d * 32 + cs2 * 8 + co * 2) = (u32)la[i] | ((u32)lb[i] << 16);
            }
            // new Er window rows (t_local 64..95 of this tile's window)
            stage_er(e0base + 32 * jt + 64);
        }
        __syncthreads();  // B2: staging visible

        // ---- S = Q.K^T (12 MFMAs) ----
        f32x4 sacc[2];
#pragma unroll
        for (int i = 0; i < 2; ++i) { sacc[i][0]=0.f; sacc[i][1]=0.f; sacc[i][2]=0.f; sacc[i][3]=0.f; }
        __builtin_amdgcn_s_setprio(1);
#pragma unroll
        for (int ks = 0; ks < 2; ++ks)
#pragma unroll
            for (int cf = 0; cf < 2; ++cf) {
                const int rk = cf * 16 + l4;
                const int cb = (ks * 4 + lh) ^ (rk & 7);
                const bf16x8 bkh = *(const bf16x8*)(k_h + rk * 64 + cb * 8);
                const bf16x8 bkl = *(const bf16x8*)(k_l + rk * 64 + cb * 8);
                sacc[cf] = __builtin_amdgcn_mfma_f32_16x16x32_bf16(aqh[ks], bkh, sacc[cf], 0, 0, 0);
                sacc[cf] = __builtin_amdgcn_mfma_f32_16x16x32_bf16(aqh[ks], bkl, sacc[cf], 0, 0, 0);
                sacc[cf] = __builtin_amdgcn_mfma_f32_16x16x32_bf16(aql[ks], bkh, sacc[cf], 0, 0, 0);
            }
        __builtin_amdgcn_s_setprio(0);

        // ---- R for the 32 new rows (12 MFMAs; ring rows wave-private) ----
        compute_R(32 * phW);

        // ---- online softmax + rel add (ring diagonal reads) ----
        float pvv[2][4];
#pragma unroll
        for (int rr = 0; rr < 4; ++rr) {
            const int sr = 16 * w + lh * 4 + rr;
            const int v0 = 32 * phR + 63 + l4 - sr;
            const int s0i = v0 - (v0 >= 96 ? 96 : 0);
            const int v1 = v0 + 16;
            const int s1i = v1 - (v1 >= 96 ? 96 : 0);
            float s0 = sacc[0][rr] + ring[sr * 101 + s0i];
            float s1 = sacc[1][rr] + ring[sr * 101 + s1i];
            if (jt >= 2 * qt) {
                const int joff = j0 - i0;             // 0 or 32
                if (joff + l4 > sr)      s0 = -3.0e38f;
                if (joff + l4 + 16 > sr) s1 = -3.0e38f;
            }
            float mt = fmaxf(s0, s1);
            mt = fmaxf(mt, __shfl_xor(mt, 1, 16));
            mt = fmaxf(mt, __shfl_xor(mt, 2, 16));
            mt = fmaxf(mt, __shfl_xor(mt, 4, 16));
            mt = fmaxf(mt, __shfl_xor(mt, 8, 16));
            const float mnew  = fmaxf(m_run[rr], mt);
            const float alpha = __builtin_amdgcn_exp2f((m_run[rr] - mnew) * cexp);
            m_run[rr] = mnew;
            const float p0 = __builtin_amdgcn_exp2f((s0 - mnew) * cexp);
            const float p1 = __builtin_amdgcn_exp2f((s1 - mnew) * cexp);
            pvv[0][rr] = p0; pvv[1][rr] = p1;
            float rs = p0 + p1;
            rs += __shfl_xor(rs, 1, 16);
            rs += __shfl_xor(rs, 2, 16);
            rs += __shfl_xor(rs, 4, 16);
            rs += __shfl_xor(rs, 8, 16);
            l_run[rr] = l_run[rr] * alpha + rs;
#pragma unroll
            for (int cfd = 0; cfd < 4; ++cfd) acc_o[cfd][rr] *= alpha;
        }

        // ---- write P (hi/lo, swizzled; rows wave-private) ----
#pragma unroll
        for (int cf = 0; cf < 2; ++cf)
#pragma unroll
            for (int rr = 0; rr < 4; ++rr) {
                const int pr = 16 * w + lh * 4 + rr;
                const int jc = l4 + 16 * cf;
                const int fp = (pr + (pr >> 2)) & 3;
                const int cs = (jc >> 3) ^ fp;
                u16 h, lo;
                split2(pvv[cf][rr], h, lo);
                p_h[pr * 32 + cs * 8 + (jc & 7)] = h;
                p_l[pr * 32 + cs * 8 + (jc & 7)] = lo;
            }

        // ---- O += P @ V (12 MFMAs; A rows + P rows wave-private) ----
        {
            const int ap = 16 * w + l4;
            const int ca = lh ^ ((ap + (ap >> 2)) & 3);
            const bf16x8 aph = *(const bf16x8*)(p_h + ap * 32 + ca * 8);
            const bf16x8 apl = *(const bf16x8*)(p_l + ap * 32 + ca * 8);
            __builtin_amdgcn_s_setprio(1);
#pragma unroll
            for (int cfd = 0; cfd < 4; ++cfd) {
                const int rn = cfd * 16 + l4;
                const int cb = lh ^ ((rn + (rn >> 2)) & 3);
                const bf16x8 bvh = *(const bf16x8*)(vt_h + rn * 32 + cb * 8);
                const bf16x8 bvl = *(const bf16x8*)(vt_l + rn * 32 + cb * 8);
                acc_o[cfd] = __builtin_amdgcn_mfma_f32_16x16x32_bf16(aph, bvh, acc_o[cfd], 0, 0, 0);
                acc_o[cfd] = __builtin_amdgcn_mfma_f32_16x16x32_bf16(aph, bvl, acc_o[cfd], 0, 0, 0);
                acc_o[cfd] = __builtin_amdgcn_mfma_f32_16x16x32_bf16(apl, bvh, acc_o[cfd], 0, 0, 0);
            }
            __builtin_amdgcn_s_setprio(0);
        }
    }

    // ---- epilogue: O /= l, split bf16, write y [B,L,D] ----
#pragma unroll
    for (int rr = 0; rr < 4; ++rr) {
        const float inv = 1.0f / l_run[rr];
        const int row = 16 * w + lh * 4 + rr;
#pragma unroll
        for (int cfd = 0; cfd < 4; ++cfd) {
            const int d = l4 + 16 * cfd;
            u16 h, lo;
            split2(acc_o[cfd][rr] * inv, h, lo);
            const size_t o = ((size_t)(bidx * LSEQ + i0 + row)) * DMODEL + hidx * HSIZE + d;
            Yh[o] = h;
            Yl[o] = lo;
        }
    }
}

// ---------------------------------------------------------------------------
extern "C" void kernel_launch(void* const* d_in, const int* in_sizes, int n_in,
                              void* d_out, int out_size, void* d_ws, size_t ws_size,
                              hipStream_t stream)
{
    (void)in_sizes; (void)n_in; (void)out_size; (void)ws_size;
    const float* x      = (const float*)d_in[0];
    const float* W_attn = (const float*)d_in[1];
    const float* b_attn = (const float*)d_in[2];
    const float* Er     = (const float*)d_in[3];
    const float* W_proj = (const float*)d_in[4];
    const float* b_proj = (const float*)d_in[5];
    float* out = (float*)d_out;

    // workspace (~152 MB); yh/yl alias xh/xl (x consumed before attn writes y)
    char* ws = (char*)d_ws;
    size_t off = 0;
    const size_t qkvb = (size_t)BATCH * NHEAD * LSEQ * HSIZE * 2;  // 16.78MB
    u16* qh = (u16*)(ws + off); off += qkvb;
    u16* ql = (u16*)(ws + off); off += qkvb;
    u16* kh = (u16*)(ws + off); off += qkvb;
    u16* kl = (u16*)(ws + off); off += qkvb;
    u16* vh = (u16*)(ws + off); off += qkvb;
    u16* vl = (u16*)(ws + off); off += qkvb;
    u16* xh = (u16*)(ws + off); off += (size_t)BATCH * LSEQ * DMODEL * 2;
    u16* xl = (u16*)(ws + off); off += (size_t)BATCH * LSEQ * DMODEL * 2;
    u16* wah = (u16*)(ws + off); off += (size_t)3 * DMODEL * DMODEL * 2;
    u16* wal = (u16*)(ws + off); off += (size_t)3 * DMODEL * DMODEL * 2;
    u16* wph = (u16*)(ws + off); off += (size_t)DMODEL * DMODEL * 2;
    u16* wpl = (u16*)(ws + off); off += (size_t)DMODEL * DMODEL * 2;
    u16* erh = (u16*)(ws + off); off += (size_t)LSEQ * HSIZE * 2;
    u16* erl = (u16*)(ws + off); off += (size_t)LSEQ * HSIZE * 2;
    u16* yh = xh;
    u16* yl = xl;

    const int M = BATCH * LSEQ;  // 8192

    // 0) split inputs to bf16 hi/lo (weights transposed to [N][K]; Er as-is)
    split_kernel<<<2048, 256, 0, stream>>>(x, xh, xl, (BATCH * LSEQ * DMODEL) / 4);
    split_kernel<<<128, 256, 0, stream>>>(Er, erh, erl, (LSEQ * HSIZE) / 4);
    splitT_kernel<<<dim3(3 * DMODEL / 32, DMODEL / 32), 256, 0, stream>>>(
        W_attn, wah, wal, DMODEL, 3 * DMODEL);
    splitT_kernel<<<dim3(DMODEL / 32, DMODEL / 32), 256, 0, stream>>>(
        W_proj, wph, wpl, DMODEL, DMODEL);

    // 1) qkv = x @ W_attn + b_attn  -> q/k/v bf16 hi/lo [B,NH,L,HS]
    mfma_gemm<0><<<dim3(3 * DMODEL / 128, M / 128), 256, 0, stream>>>(
        xh, xl, wah, wal, b_attn, nullptr, qh, ql, kh, kl, vh, vl, M, 3 * DMODEL, DMODEL);

    // 2) MFMA flash attention (rolling-R) -> y (bf16 hi/lo)
    attn_kernel<<<BATCH * NHEAD * (LSEQ / 64), 256, 0, stream>>>(
        qh, ql, kh, kl, vh, vl, erh, erl, yh, yl);

    // 3) out = y @ W_proj + b_proj
    mfma_gemm<1><<<dim3(DMODEL / 128, M / 128), 256, 0, stream>>>(
        yh, yl, wph, wpl, b_proj, out, nullptr, nullptr, nullptr, nullptr, nullptr, nullptr,
        M, DMODEL, DMODEL);
}

// Round 9
// 716.051 us; speedup vs baseline: 2.6116x; 1.0514x over previous
//
#include <hip/hip_runtime.h>
#include <cstdint>

#define BATCH  4
#define LSEQ   2048
#define DMODEL 1024
#define NHEAD  16
#define HSIZE  64

typedef __attribute__((ext_vector_type(8))) short bf16x8;
typedef __attribute__((ext_vector_type(4))) float f32x4;
typedef unsigned short u16;
typedef unsigned int u32;

// ---------------------------------------------------------------------------
// XCD-aware bijective block swizzle (m157; valid when n % 8 == 0).
// ---------------------------------------------------------------------------
__device__ __forceinline__ int xcd_swz(int lin, int n) {
    return (lin & 7) * (n >> 3) + (lin >> 3);
}

// ---------------------------------------------------------------------------
// bf16 split helpers (round-to-nearest-even)
// ---------------------------------------------------------------------------
__device__ __forceinline__ u16 f2b(float f) {
    unsigned int u = __float_as_uint(f);
    return (u16)((u + 0x7FFFu + ((u >> 16) & 1u)) >> 16);
}
__device__ __forceinline__ float b2f(u16 h) {
    return __uint_as_float(((unsigned int)h) << 16);
}
__device__ __forceinline__ void split2(float x, u16& h, u16& l) {
    h = f2b(x);
    l = f2b(x - b2f(h));
}

__device__ __forceinline__ void gld16(const void* g, void* l) {
    __builtin_amdgcn_global_load_lds(
        (const __attribute__((address_space(1))) unsigned int*)g,
        (__attribute__((address_space(3))) unsigned int*)l, 16, 0, 0);
}

// ---------------------------------------------------------------------------
// split fp32 -> bf16 hi/lo (grid-stride, float4)
// ---------------------------------------------------------------------------
__global__ void split_kernel(const float* __restrict__ in,
                             u16* __restrict__ hi, u16* __restrict__ lo, int n4)
{
    for (int i = blockIdx.x * blockDim.x + threadIdx.x; i < n4;
         i += gridDim.x * blockDim.x) {
        const float4 v = ((const float4*)in)[i];
        ushort4 h, l;
        split2(v.x, h.x, l.x);
        split2(v.y, h.y, l.y);
        split2(v.z, h.z, l.z);
        split2(v.w, h.w, l.w);
        ((ushort4*)hi)[i] = h;
        ((ushort4*)lo)[i] = l;
    }
}

// ---------------------------------------------------------------------------
// transpose + split: in [K][N] fp32 -> hi/lo [N][K] bf16
// ---------------------------------------------------------------------------
__global__ __launch_bounds__(256)
void splitT_kernel(const float* __restrict__ in,
                   u16* __restrict__ hi, u16* __restrict__ lo, int K, int N)
{
    __shared__ float t[32][33];
    const int k0 = blockIdx.y * 32, n0 = blockIdx.x * 32;
    const int tx = threadIdx.x & 7, ty = threadIdx.x >> 3;   // 8 x 32

    const float4 v = *(const float4*)(in + (size_t)(k0 + ty) * N + n0 + tx * 4);
    t[ty][tx * 4 + 0] = v.x;
    t[ty][tx * 4 + 1] = v.y;
    t[ty][tx * 4 + 2] = v.z;
    t[ty][tx * 4 + 3] = v.w;
    __syncthreads();

    const float x0 = t[tx * 4 + 0][ty], x1 = t[tx * 4 + 1][ty];
    const float x2 = t[tx * 4 + 2][ty], x3 = t[tx * 4 + 3][ty];
    ushort4 h, l;
    split2(x0, h.x, l.x);
    split2(x1, h.y, l.y);
    split2(x2, h.z, l.z);
    split2(x3, h.w, l.w);
    const size_t o = (size_t)(n0 + ty) * K + k0 + tx * 4;
    *(ushort4*)(hi + o) = h;
    *(ushort4*)(lo + o) = l;
}

// ---------------------------------------------------------------------------
// Split-bf16 MFMA GEMM (m97 structure, HW-validated round 4).
// MODE 0: epilogue splits to bf16 hi/lo and scatters to q/k/v [B,NH,L,HS].
// MODE 1: row-major fp32 C.
// ---------------------------------------------------------------------------
template<int MODE>
__global__ __launch_bounds__(256)
void mfma_gemm(const u16* __restrict__ Ah, const u16* __restrict__ Al,
               const u16* __restrict__ Bh, const u16* __restrict__ Bl,
               const float* __restrict__ bias, float* __restrict__ C0,
               u16* __restrict__ Qh, u16* __restrict__ Ql,
               u16* __restrict__ Kh, u16* __restrict__ Kl,
               u16* __restrict__ Vh, u16* __restrict__ Vl,
               int M, int N, int K)
{
    __shared__ __align__(16) u16 sAh[128 * 32];
    __shared__ __align__(16) u16 sAl[128 * 32];
    __shared__ __align__(16) u16 sBh[128 * 32];
    __shared__ __align__(16) u16 sBl[128 * 32];

    const int tid = threadIdx.x;
    const int lane = tid & 63, wave = tid >> 6;
    const int wm = wave >> 1, wn = wave & 1;

    const int gx = gridDim.x;
    int lin = blockIdx.y * gx + blockIdx.x;
    lin = xcd_swz(lin, gx * gridDim.y);
    const int m0 = (lin / gx) * 128, n0 = (lin % gx) * 128;

    f32x4 acc[4][4];
#pragma unroll
    for (int mi = 0; mi < 4; ++mi)
#pragma unroll
        for (int ni = 0; ni < 4; ++ni) {
            acc[mi][ni][0] = 0.f; acc[mi][ni][1] = 0.f;
            acc[mi][ni][2] = 0.f; acc[mi][ni][3] = 0.f;
        }

    const int srow = lane >> 2;
    const int skc8 = (lane & 3) * 8;
    const int r0 = wave * 32;

    for (int kt = 0; kt < K; kt += 32) {
        __syncthreads();
#pragma unroll
        for (int g = 0; g < 2; ++g) {
            const int row = r0 + g * 16 + srow;
            const size_t ga = (size_t)(m0 + row) * K + kt + skc8;
            const size_t gb = (size_t)(n0 + row) * K + kt + skc8;
            u16* la = sAh + (size_t)(r0 + g * 16) * 32;
            u16* lb = sAl + (size_t)(r0 + g * 16) * 32;
            u16* lc = sBh + (size_t)(r0 + g * 16) * 32;
            u16* ld = sBl + (size_t)(r0 + g * 16) * 32;
            gld16(Ah + ga, la);
            gld16(Al + ga, lb);
            gld16(Bh + gb, lc);
            gld16(Bl + gb, ld);
        }
        __syncthreads();

        const int fr = lane & 15, fk8 = (lane >> 4) * 8;
        bf16x8 ah[4], al[4], bh[4], bl[4];
#pragma unroll
        for (int mi = 0; mi < 4; ++mi) {
            const int off = (wm * 64 + mi * 16 + fr) * 32 + fk8;
            ah[mi] = *(const bf16x8*)(sAh + off);
            al[mi] = *(const bf16x8*)(sAl + off);
        }
#pragma unroll
        for (int ni = 0; ni < 4; ++ni) {
            const int off = (wn * 64 + ni * 16 + fr) * 32 + fk8;
            bh[ni] = *(const bf16x8*)(sBh + off);
            bl[ni] = *(const bf16x8*)(sBl + off);
        }
#pragma unroll
        for (int mi = 0; mi < 4; ++mi)
#pragma unroll
            for (int ni = 0; ni < 4; ++ni) {
                acc[mi][ni] = __builtin_amdgcn_mfma_f32_16x16x32_bf16(ah[mi], bh[ni], acc[mi][ni], 0, 0, 0);
                acc[mi][ni] = __builtin_amdgcn_mfma_f32_16x16x32_bf16(ah[mi], bl[ni], acc[mi][ni], 0, 0, 0);
                acc[mi][ni] = __builtin_amdgcn_mfma_f32_16x16x32_bf16(al[mi], bh[ni], acc[mi][ni], 0, 0, 0);
            }
    }

    // C/D frag layout: col = lane&15, row = (lane>>4)*4 + r  [m89/m91, HW-validated]
    const int cn = lane & 15, cr = (lane >> 4) * 4;
#pragma unroll
    for (int ni = 0; ni < 4; ++ni) {
        const int col = n0 + wn * 64 + ni * 16 + cn;
        const float bv = bias[col];
        if (MODE == 1) {
#pragma unroll
            for (int mi = 0; mi < 4; ++mi) {
                const int rowb = m0 + wm * 64 + mi * 16 + cr;
#pragma unroll
                for (int r = 0; r < 4; ++r)
                    C0[(size_t)(rowb + r) * N + col] = acc[mi][ni][r] + bv;
            }
        } else {
            const int sel = col >> 10, d = col & 1023;
            const int head = d >> 6, hs = d & 63;
            u16* dh = (sel == 0) ? Qh : (sel == 1) ? Kh : Vh;
            u16* dl = (sel == 0) ? Ql : (sel == 1) ? Kl : Vl;
#pragma unroll
            for (int mi = 0; mi < 4; ++mi) {
                const int rowb = m0 + wm * 64 + mi * 16 + cr;
#pragma unroll
                for (int r = 0; r < 4; ++r) {
                    const int m = rowb + r;
                    const int bb = m >> 11, l = m & (LSEQ - 1);
                    const size_t idx = (((size_t)bb * NHEAD + head) * LSEQ + l) * HSIZE + hs;
                    u16 h, lo;
                    split2(acc[mi][ni][r] + bv, h, lo);
                    dh[idx] = h;
                    dl[idx] = lo;
                }
            }
        }
    }
}

// ---------------------------------------------------------------------------
// MFMA flash attention with relative positions (split-bf16, 3-term).
// Block = (b,h,qtile of 64 rows); 4 waves, wave w owns q rows [16w,16w+16).
// KV tile 32.  Rolling-R ring[64][101] fp32 (wave-private rows), 12 R-MFMAs
// per tile for the 32 new window rows; 2-round prologue fills slots [0,64).
//   write slot = 32*((jt+2)%3) + t_new;  read slot = (32*(jt%3)+t_local)%96,
//   t_local = 63 + jc - sr.
// Q in registers as A-fragments.  K staged [32][64] swizzled c^(row&7);
// V^T packed-u32 [64][16] and P [64][32] swizzled chunk^((row+(row>>2))&3).
// T14: K/V/Er global loads for tile jt+1 issued right after B2, consumed as
// pure ds_writes at the next B1->B2 window (staging latency off the
// critical path; round-7 was latency-bound: MfmaUtil 14%, VALU 34%).
// This round: Er staging buffers ALIAS the P buffers (E consumed by R-MFMAs
// strictly before P produced; new cross-wave hazard closed by barrier B3
// between compute_R and the P write).  LDS 57.25 -> 49.25 KiB => 3 blocks/CU
// (occupancy 18% -> ~27%), attacking the same latency-bound diagnosis via TLP.
// T5 setprio around MFMA clusters.
// ---------------------------------------------------------------------------
__global__ __launch_bounds__(256)
void attn_kernel(const u16* __restrict__ Qh, const u16* __restrict__ Ql,
                 const u16* __restrict__ Kh, const u16* __restrict__ Kl,
                 const u16* __restrict__ Vh, const u16* __restrict__ Vl,
                 const u16* __restrict__ Eh, const u16* __restrict__ El,
                 u16* __restrict__ Yh, u16* __restrict__ Yl)
{
    const int nqt = LSEQ / 64;            // 32
    const int lin = xcd_swz(blockIdx.x, BATCH * NHEAD * nqt);
    const int bh = lin / nqt;
    const int qt = (nqt - 1) - (lin % nqt);   // longest blocks first
    const int i0 = qt * 64;
    const int bidx = bh >> 4, hidx = bh & 15;

    const size_t bho = (size_t)bh * LSEQ * HSIZE;
    const u16* Qph = Qh + bho; const u16* Qpl = Ql + bho;
    const u16* Kph = Kh + bho; const u16* Kpl = Kl + bho;
    const u16* Vph = Vh + bho; const u16* Vpl = Vl + bho;

    // 49.25 KiB total -> 3 blocks/CU
    __shared__ __align__(16) unsigned char smem[50432];
    u16* k_h  = (u16*)(smem);              // [32][64] 4096B
    u16* k_l  = (u16*)(smem + 4096);
    u16* vt_h = (u16*)(smem + 8192);       // [64][16] u32-packed (V^T) 4096B
    u16* vt_l = (u16*)(smem + 12288);
    u16* e_h  = (u16*)(smem + 16384);      // [32][64] 4096B (new window rows)
    u16* e_l  = (u16*)(smem + 20480);
    u16* p_h  = (u16*)(smem + 16384);      // [64][32] 4096B — ALIASES e_h
    u16* p_l  = (u16*)(smem + 20480);      //                  ALIASES e_l
    float* ring = (float*)(smem + 24576);  // [64][101] fp32, 25856B

    const int tid = threadIdx.x;
    const int lane = tid & 63, w = tid >> 6;
    const int l4 = lane & 15, lh = lane >> 4;

    // ---- Q A-fragments in registers (rows 16w+l4, chunk ks*4+lh) ----
    bf16x8 aqh[2], aql[2];
#pragma unroll
    for (int ks = 0; ks < 2; ++ks) {
        const size_t qoff = (size_t)(i0 + 16 * w + l4) * 64 + ks * 32 + lh * 8;
        aqh[ks] = *(const bf16x8*)(Qph + qoff);
        aql[ks] = *(const bf16x8*)(Qpl + qoff);
    }

    f32x4 acc_o[4];
#pragma unroll
    for (int i = 0; i < 4; ++i) {
        acc_o[i][0] = 0.f; acc_o[i][1] = 0.f; acc_o[i][2] = 0.f; acc_o[i][3] = 0.f;
    }
    float m_run[4], l_run[4];
#pragma unroll
    for (int i = 0; i < 4; ++i) { m_run[i] = -3.0e38f; l_run[i] = 0.f; }

    const float cexp = 0.18033688011112042f;  // (1/sqrt(64)) * log2(e)
    const int e0base = LSEQ - 64 - i0;        // e0(jt=0) >= 0
    const int ntiles = 2 * qt + 2;

    const int ser = tid >> 3, sec = tid & 7;  // K/Er staging: row, chunk
    const int jp = tid >> 4, d4v = (tid & 15) * 4;  // V staging coords

    // ---- T14 prefetch registers ----
    bf16x8 pk_h, pk_l, pe_h, pe_l;
    ushort4 pvA_h, pvB_h, pvA_l, pvB_l;
    auto prefetch = [&](int jt) {
        const int j0 = jt * 32;
        pk_h = *(const bf16x8*)(Kph + (size_t)(j0 + ser) * 64 + sec * 8);
        pk_l = *(const bf16x8*)(Kpl + (size_t)(j0 + ser) * 64 + sec * 8);
        pvA_h = *(const ushort4*)(Vph + (size_t)(j0 + 2 * jp) * 64 + d4v);
        pvB_h = *(const ushort4*)(Vph + (size_t)(j0 + 2 * jp + 1) * 64 + d4v);
        pvA_l = *(const ushort4*)(Vpl + (size_t)(j0 + 2 * jp) * 64 + d4v);
        pvB_l = *(const ushort4*)(Vpl + (size_t)(j0 + 2 * jp + 1) * 64 + d4v);
        const int g = e0base + 32 * jt + 64 + ser;
        if (g < LSEQ) {
            pe_h = *(const bf16x8*)(Eh + (size_t)g * 64 + sec * 8);
            pe_l = *(const bf16x8*)(El + (size_t)g * 64 + sec * 8);
        } else {
            pe_h = (bf16x8){0, 0, 0, 0, 0, 0, 0, 0};
            pe_l = (bf16x8){0, 0, 0, 0, 0, 0, 0, 0};
        }
    };

    // stage 32 Er rows [g0, g0+32) directly (prologue only)
    auto stage_er = [&](int g0) {
        const int g = g0 + ser;
        bf16x8 zh = {0, 0, 0, 0, 0, 0, 0, 0}, zl = {0, 0, 0, 0, 0, 0, 0, 0};
        if (g < LSEQ) {
            zh = *(const bf16x8*)(Eh + (size_t)g * 64 + sec * 8);
            zl = *(const bf16x8*)(El + (size_t)g * 64 + sec * 8);
        }
        const int cs = sec ^ (ser & 7);
        *(bf16x8*)(e_h + ser * 64 + cs * 8) = zh;
        *(bf16x8*)(e_l + ser * 64 + cs * 8) = zl;
    };

    // 12 MFMAs over staged e rows -> ring slots [slotbase, slotbase+32)
    auto compute_R = [&](int slotbase) {
        f32x4 racc[2];
#pragma unroll
        for (int i = 0; i < 2; ++i) { racc[i][0]=0.f; racc[i][1]=0.f; racc[i][2]=0.f; racc[i][3]=0.f; }
        __builtin_amdgcn_s_setprio(1);
#pragma unroll
        for (int ks = 0; ks < 2; ++ks)
#pragma unroll
            for (int nf = 0; nf < 2; ++nf) {
                const int re = nf * 16 + l4;
                const int cb = (ks * 4 + lh) ^ (re & 7);
                const bf16x8 beh = *(const bf16x8*)(e_h + re * 64 + cb * 8);
                const bf16x8 bel = *(const bf16x8*)(e_l + re * 64 + cb * 8);
                racc[nf] = __builtin_amdgcn_mfma_f32_16x16x32_bf16(aqh[ks], beh, racc[nf], 0, 0, 0);
                racc[nf] = __builtin_amdgcn_mfma_f32_16x16x32_bf16(aqh[ks], bel, racc[nf], 0, 0, 0);
                racc[nf] = __builtin_amdgcn_mfma_f32_16x16x32_bf16(aql[ks], beh, racc[nf], 0, 0, 0);
            }
        __builtin_amdgcn_s_setprio(0);
#pragma unroll
        for (int nf = 0; nf < 2; ++nf)
#pragma unroll
            for (int r = 0; r < 4; ++r)
                ring[(16 * w + lh * 4 + r) * 101 + slotbase + nf * 16 + l4] = racc[nf][r];
    };

    // issue tile-0 prefetch immediately (in flight across the prologue)
    prefetch(0);

    // ---- prologue: fill ring slots [0,64) = window-0 t_local [0,64) ----
#pragma unroll
    for (int p = 0; p < 2; ++p) {
        __syncthreads();
        stage_er(e0base + 32 * p);
        __syncthreads();
        compute_R(32 * p);
    }

    for (int jt = 0; jt < ntiles; ++jt) {
        const int j0 = jt * 32;
        const int phR = jt % 3;               // read phase
        const int phW = (jt + 2) % 3;         // write phase (t_local 64..95)

        __syncthreads();  // B1: prev-tile PV reads + prev R-MFMA e-reads done
        {
            // ---- STAGE_WRITE from prefetch regs (pure ds_write) ----
            const int cs = sec ^ (ser & 7);
            *(bf16x8*)(k_h + ser * 64 + cs * 8) = pk_h;
            *(bf16x8*)(k_l + ser * 64 + cs * 8) = pk_l;
            *(bf16x8*)(e_h + ser * 64 + cs * 8) = pe_h;
            *(bf16x8*)(e_l + ser * 64 + cs * 8) = pe_l;
            // V^T packed u32 [64][16]: u32 jp packs (j=2jp, 2jp+1) at dim d
            const u16 ha[4] = {pvA_h.x, pvA_h.y, pvA_h.z, pvA_h.w};
            const u16 hb[4] = {pvB_h.x, pvB_h.y, pvB_h.z, pvB_h.w};
            const u16 la[4] = {pvA_l.x, pvA_l.y, pvA_l.z, pvA_l.w};
            const u16 lb[4] = {pvB_l.x, pvB_l.y, pvB_l.z, pvB_l.w};
            const int cq = jp >> 2, co = jp & 3;
#pragma unroll
            for (int i = 0; i < 4; ++i) {
                const int d = d4v + i;
                const int fd = (d + (d >> 2)) & 3;
                const int cs2 = cq ^ fd;
                *(u32*)(vt_h + d * 32 + cs2 * 8 + co * 2) = (u32)ha[i] | ((u32)hb[i] << 16);
                *(u32*)(vt_l + d * 32 + cs2 * 8 + co * 2) = (u32)la[i] | ((u32)lb[i] << 16);
            }
        }
        __syncthreads();  // B2: staging visible

        // ---- issue next tile's prefetch (in flight across compute) ----
        if (jt + 1 < ntiles) prefetch(jt + 1);

        // ---- S = Q.K^T (12 MFMAs) ----
        f32x4 sacc[2];
#pragma unroll
        for (int i = 0; i < 2; ++i) { sacc[i][0]=0.f; sacc[i][1]=0.f; sacc[i][2]=0.f; sacc[i][3]=0.f; }
        __builtin_amdgcn_s_setprio(1);
#pragma unroll
        for (int ks = 0; ks < 2; ++ks)
#pragma unroll
            for (int cf = 0; cf < 2; ++cf) {
                const int rk = cf * 16 + l4;
                const int cb = (ks * 4 + lh) ^ (rk & 7);
                const bf16x8 bkh = *(const bf16x8*)(k_h + rk * 64 + cb * 8);
                const bf16x8 bkl = *(const bf16x8*)(k_l + rk * 64 + cb * 8);
                sacc[cf] = __builtin_amdgcn_mfma_f32_16x16x32_bf16(aqh[ks], bkh, sacc[cf], 0, 0, 0);
                sacc[cf] = __builtin_amdgcn_mfma_f32_16x16x32_bf16(aqh[ks], bkl, sacc[cf], 0, 0, 0);
                sacc[cf] = __builtin_amdgcn_mfma_f32_16x16x32_bf16(aql[ks], bkh, sacc[cf], 0, 0, 0);
            }
        __builtin_amdgcn_s_setprio(0);

        // ---- R for the 32 new rows (12 MFMAs; ring rows wave-private) ----
        compute_R(32 * phW);

        // ---- online softmax + rel add (ring diagonal reads) ----
        float pvv[2][4];
#pragma unroll
        for (int rr = 0; rr < 4; ++rr) {
            const int sr = 16 * w + lh * 4 + rr;
            const int v0 = 32 * phR + 63 + l4 - sr;
            const int s0i = v0 - (v0 >= 96 ? 96 : 0);
            const int v1 = v0 + 16;
            const int s1i = v1 - (v1 >= 96 ? 96 : 0);
            float s0 = sacc[0][rr] + ring[sr * 101 + s0i];
            float s1 = sacc[1][rr] + ring[sr * 101 + s1i];
            if (jt >= 2 * qt) {
                const int joff = j0 - i0;             // 0 or 32
                if (joff + l4 > sr)      s0 = -3.0e38f;
                if (joff + l4 + 16 > sr) s1 = -3.0e38f;
            }
            float mt = fmaxf(s0, s1);
            mt = fmaxf(mt, __shfl_xor(mt, 1, 16));
            mt = fmaxf(mt, __shfl_xor(mt, 2, 16));
            mt = fmaxf(mt, __shfl_xor(mt, 4, 16));
            mt = fmaxf(mt, __shfl_xor(mt, 8, 16));
            const float mnew  = fmaxf(m_run[rr], mt);
            const float alpha = __builtin_amdgcn_exp2f((m_run[rr] - mnew) * cexp);
            m_run[rr] = mnew;
            const float p0 = __builtin_amdgcn_exp2f((s0 - mnew) * cexp);
            const float p1 = __builtin_amdgcn_exp2f((s1 - mnew) * cexp);
            pvv[0][rr] = p0; pvv[1][rr] = p1;
            float rs = p0 + p1;
            rs += __shfl_xor(rs, 1, 16);
            rs += __shfl_xor(rs, 2, 16);
            rs += __shfl_xor(rs, 4, 16);
            rs += __shfl_xor(rs, 8, 16);
            l_run[rr] = l_run[rr] * alpha + rs;
#pragma unroll
            for (int cfd = 0; cfd < 4; ++cfd) acc_o[cfd][rr] *= alpha;
        }

        __syncthreads();  // B3: all waves' R-MFMA e-reads done (P aliases E)

        // ---- write P (hi/lo, swizzled; rows wave-private) ----
#pragma unroll
        for (int cf = 0; cf < 2; ++cf)
#pragma unroll
            for (int rr = 0; rr < 4; ++rr) {
                const int pr = 16 * w + lh * 4 + rr;
                const int jc = l4 + 16 * cf;
                const int fp = (pr + (pr >> 2)) & 3;
                const int cs = (jc >> 3) ^ fp;
                u16 h, lo;
                split2(pvv[cf][rr], h, lo);
                p_h[pr * 32 + cs * 8 + (jc & 7)] = h;
                p_l[pr * 32 + cs * 8 + (jc & 7)] = lo;
            }

        // ---- O += P @ V (12 MFMAs; A rows wave-private, same-wave ds order) ----
        {
            const int ap = 16 * w + l4;
            const int ca = lh ^ ((ap + (ap >> 2)) & 3);
            const bf16x8 aph = *(const bf16x8*)(p_h + ap * 32 + ca * 8);
            const bf16x8 apl = *(const bf16x8*)(p_l + ap * 32 + ca * 8);
            __builtin_amdgcn_s_setprio(1);
#pragma unroll
            for (int cfd = 0; cfd < 4; ++cfd) {
                const int rn = cfd * 16 + l4;
                const int cb = lh ^ ((rn + (rn >> 2)) & 3);
                const bf16x8 bvh = *(const bf16x8*)(vt_h + rn * 32 + cb * 8);
                const bf16x8 bvl = *(const bf16x8*)(vt_l + rn * 32 + cb * 8);
                acc_o[cfd] = __builtin_amdgcn_mfma_f32_16x16x32_bf16(aph, bvh, acc_o[cfd], 0, 0, 0);
                acc_o[cfd] = __builtin_amdgcn_mfma_f32_16x16x32_bf16(aph, bvl, acc_o[cfd], 0, 0, 0);
                acc_o[cfd] = __builtin_amdgcn_mfma_f32_16x16x32_bf16(apl, bvh, acc_o[cfd], 0, 0, 0);
            }
            __builtin_amdgcn_s_setprio(0);
        }
    }

    // ---- epilogue: O /= l, split bf16, write y [B,L,D] ----
#pragma unroll
    for (int rr = 0; rr < 4; ++rr) {
        const float inv = 1.0f / l_run[rr];
        const int row = 16 * w + lh * 4 + rr;
#pragma unroll
        for (int cfd = 0; cfd < 4; ++cfd) {
            const int d = l4 + 16 * cfd;
            u16 h, lo;
            split2(acc_o[cfd][rr] * inv, h, lo);
            const size_t o = ((size_t)(bidx * LSEQ + i0 + row)) * DMODEL + hidx * HSIZE + d;
            Yh[o] = h;
            Yl[o] = lo;
        }
    }
}

// ---------------------------------------------------------------------------
extern "C" void kernel_launch(void* const* d_in, const int* in_sizes, int n_in,
                              void* d_out, int out_size, void* d_ws, size_t ws_size,
                              hipStream_t stream)
{
    (void)in_sizes; (void)n_in; (void)out_size; (void)ws_size;
    const float* x      = (const float*)d_in[0];
    const float* W_attn = (const float*)d_in[1];
    const float* b_attn = (const float*)d_in[2];
    const float* Er     = (const float*)d_in[3];
    const float* W_proj = (const float*)d_in[4];
    const float* b_proj = (const float*)d_in[5];
    float* out = (float*)d_out;

    // workspace (~152 MB); yh/yl alias xh/xl (x consumed before attn writes y)
    char* ws = (char*)d_ws;
    size_t off = 0;
    const size_t qkvb = (size_t)BATCH * NHEAD * LSEQ * HSIZE * 2;  // 16.78MB
    u16* qh = (u16*)(ws + off); off += qkvb;
    u16* ql = (u16*)(ws + off); off += qkvb;
    u16* kh = (u16*)(ws + off); off += qkvb;
    u16* kl = (u16*)(ws + off); off += qkvb;
    u16* vh = (u16*)(ws + off); off += qkvb;
    u16* vl = (u16*)(ws + off); off += qkvb;
    u16* xh = (u16*)(ws + off); off += (size_t)BATCH * LSEQ * DMODEL * 2;
    u16* xl = (u16*)(ws + off); off += (size_t)BATCH * LSEQ * DMODEL * 2;
    u16* wah = (u16*)(ws + off); off += (size_t)3 * DMODEL * DMODEL * 2;
    u16* wal = (u16*)(ws + off); off += (size_t)3 * DMODEL * DMODEL * 2;
    u16* wph = (u16*)(ws + off); off += (size_t)DMODEL * DMODEL * 2;
    u16* wpl = (u16*)(ws + off); off += (size_t)DMODEL * DMODEL * 2;
    u16* erh = (u16*)(ws + off); off += (size_t)LSEQ * HSIZE * 2;
    u16* erl = (u16*)(ws + off); off += (size_t)LSEQ * HSIZE * 2;
    u16* yh = xh;
    u16* yl = xl;

    const int M = BATCH * LSEQ;  // 8192

    // 0) split inputs to bf16 hi/lo (weights transposed to [N][K]; Er as-is)
    split_kernel<<<2048, 256, 0, stream>>>(x, xh, xl, (BATCH * LSEQ * DMODEL) / 4);
    split_kernel<<<128, 256, 0, stream>>>(Er, erh, erl, (LSEQ * HSIZE) / 4);
    splitT_kernel<<<dim3(3 * DMODEL / 32, DMODEL / 32), 256, 0, stream>>>(
        W_attn, wah, wal, DMODEL, 3 * DMODEL);
    splitT_kernel<<<dim3(DMODEL / 32, DMODEL / 32), 256, 0, stream>>>(
        W_proj, wph, wpl, DMODEL, DMODEL);

    // 1) qkv = x @ W_attn + b_attn  -> q/k/v bf16 hi/lo [B,NH,L,HS]
    mfma_gemm<0><<<dim3(3 * DMODEL / 128, M / 128), 256, 0, stream>>>(
        xh, xl, wah, wal, b_attn, nullptr, qh, ql, kh, kl, vh, vl, M, 3 * DMODEL, DMODEL);

    // 2) MFMA flash attention (rolling-R + T14 prefetch + E/P alias) -> y
    attn_kernel<<<BATCH * NHEAD * (LSEQ / 64), 256, 0, stream>>>(
        qh, ql, kh, kl, vh, vl, erh, erl, yh, yl);

    // 3) out = y @ W_proj + b_proj
    mfma_gemm<1><<<dim3(DMODEL / 128, M / 128), 256, 0, stream>>>(
        yh, yl, wph, wpl, b_proj, out, nullptr, nullptr, nullptr, nullptr, nullptr, nullptr,
        M, DMODEL, DMODEL);
}